// Round 6
// baseline (2509.341 us; speedup 1.0000x reference)
//
#include <hip/hip_runtime.h>

#define N_NODES 50000
#define N_EDGES 1600000
#define NREL 32
#define NBASES 8
#define DIN 128
#define DOUT 128
#define KTOT (NBASES * DIN)       // 1024
#define KSL (KTOT + DIN)          // 1152 (self-loop folded in)
#define NODES_PER_BLOCK 8

// ---------------- CSR build ----------------

__global__ void k_hist(const int* __restrict__ dst, int* __restrict__ deg) {
    int e = blockIdx.x * blockDim.x + threadIdx.x;
    if (e < N_EDGES) atomicAdd(&deg[dst[e]], 1);
}

__global__ void k_scan(const int* __restrict__ deg, int* __restrict__ indptr) {
    __shared__ int sdata[1024];
    const int T = 1024;
    int t = threadIdx.x;
    const int chunk = (N_NODES + T - 1) / T;
    int lo = t * chunk;
    int hi = lo + chunk; if (hi > N_NODES) hi = N_NODES;
    if (lo > N_NODES) lo = N_NODES;
    int s = 0;
    for (int i = lo; i < hi; ++i) s += deg[i];
    sdata[t] = s;
    __syncthreads();
    for (int off = 1; off < T; off <<= 1) {
        int v = (t >= off) ? sdata[t - off] : 0;
        __syncthreads();
        sdata[t] += v;
        __syncthreads();
    }
    int base = (t == 0) ? 0 : sdata[t - 1];
    for (int i = lo; i < hi; ++i) { indptr[i] = base; base += deg[i]; }
    if (t == T - 1) indptr[N_NODES] = sdata[T - 1];
}

// writes dst-sorted packed records: src | (etype << 16)
__global__ void k_scatter(const int* __restrict__ dst,
                          const int* __restrict__ src,
                          const int* __restrict__ ety,
                          const int* __restrict__ indptr,
                          int* __restrict__ cursor,
                          int* __restrict__ packed) {
    int e = blockIdx.x * blockDim.x + threadIdx.x;
    if (e < N_EDGES) {
        int d = dst[e];
        int pos = atomicAdd(&cursor[d], 1);
        packed[indptr[d] + pos] = src[e] | (ety[e] << 16);
    }
}

// ---------------- fused aggregate + project ----------------
// Block: 256 threads (4 waves), 8 dst nodes.
// Phase 1: wave w aggregates nodes {w, w+4}; lane covers d=2*lane..2*lane+1.
//          Edge records loaded 64-wide coalesced, broadcast via __shfl;
//          4 x-row gathers in flight. Accumulators are 16 NAMED SCALARS
//          (never address-taken) so SROA keeps them in VGPRs — passing the
//          acc array by pointer (rounds 3/4) defeated alias analysis and
//          spilled the accumulator to scratch (1.8 GB of WRITE_SIZE).
// Phase 2: h = tmp[8 x 1152] @ [weight;loop_w][1152 x 128], weight read
//          straight from L2 (coalesced), tmp via LDS broadcast float4.

// 16 FMAs on named scalar accumulators; wA/wB are fresh locals per edge.
#define EDGE_FMA(P, XV)                                                      \
    do {                                                                     \
        const float4 wA_ = *(const float4*)&wc[((P) >> 16) * NBASES];        \
        const float4 wB_ = *(const float4*)&wc[((P) >> 16) * NBASES + 4];    \
        a0x += wA_.x * (XV).x; a0y += wA_.x * (XV).y;                        \
        a1x += wA_.y * (XV).x; a1y += wA_.y * (XV).y;                        \
        a2x += wA_.z * (XV).x; a2y += wA_.z * (XV).y;                        \
        a3x += wA_.w * (XV).x; a3y += wA_.w * (XV).y;                        \
        a4x += wB_.x * (XV).x; a4y += wB_.x * (XV).y;                        \
        a5x += wB_.y * (XV).x; a5y += wB_.y * (XV).y;                        \
        a6x += wB_.z * (XV).x; a6y += wB_.z * (XV).y;                        \
        a7x += wB_.w * (XV).x; a7y += wB_.w * (XV).y;                        \
    } while (0)

__launch_bounds__(256, 4)
__global__ void k_fused(const float* __restrict__ x,
                        const float* __restrict__ weight,    // [1024][128]
                        const float* __restrict__ w_comp,    // [32][8]
                        const float* __restrict__ h_bias,    // [128]
                        const float* __restrict__ loop_w,    // [128][128]
                        const int* __restrict__ indptr,
                        const int* __restrict__ packed,
                        float* __restrict__ out) {
    __shared__ __align__(16) float wc[NREL * NBASES];            // 1 KB
    __shared__ __align__(16) float tmp[NODES_PER_BLOCK][KSL];    // 36 KB

    const int tid  = threadIdx.x;
    const int lane = tid & 63;
    const int wid  = tid >> 6;                 // 0..3
    const int nbase = blockIdx.x * NODES_PER_BLOCK;

    if (tid < NREL * NBASES) wc[tid] = w_comp[tid];
    __syncthreads();

    // ---- Phase 1 ----
    for (int rep = 0; rep < 2; ++rep) {
        const int nl = wid + rep * 4;
        const int node = nbase + nl;
        float a0x = 0.f, a0y = 0.f, a1x = 0.f, a1y = 0.f;
        float a2x = 0.f, a2y = 0.f, a3x = 0.f, a3y = 0.f;
        float a4x = 0.f, a4y = 0.f, a5x = 0.f, a5y = 0.f;
        float a6x = 0.f, a6y = 0.f, a7x = 0.f, a7y = 0.f;

        if (node < N_NODES) {
            // self-loop row into LDS
            *(float2*)&tmp[nl][KTOT + 2 * lane] =
                *(const float2*)&x[(size_t)node * DIN + 2 * lane];

            const int beg = indptr[node], end = indptr[node + 1];
            for (int base = beg; base < end; base += 64) {
                const int cnt = min(64, end - base);
                int pk = 0;
                if (base + lane < end) pk = packed[base + lane];
                int j = 0;
                for (; j + 4 <= cnt; j += 4) {
                    const int p0 = __shfl(pk, j + 0);
                    const int p1 = __shfl(pk, j + 1);
                    const int p2 = __shfl(pk, j + 2);
                    const int p3 = __shfl(pk, j + 3);
                    // 4 independent gathers in flight
                    const float2 x0 = *(const float2*)&x[(size_t)(p0 & 0xFFFF) * DIN + 2 * lane];
                    const float2 x1 = *(const float2*)&x[(size_t)(p1 & 0xFFFF) * DIN + 2 * lane];
                    const float2 x2 = *(const float2*)&x[(size_t)(p2 & 0xFFFF) * DIN + 2 * lane];
                    const float2 x3 = *(const float2*)&x[(size_t)(p3 & 0xFFFF) * DIN + 2 * lane];
                    EDGE_FMA(p0, x0);
                    EDGE_FMA(p1, x1);
                    EDGE_FMA(p2, x2);
                    EDGE_FMA(p3, x3);
                }
                for (; j < cnt; ++j) {
                    const int p0 = __shfl(pk, j);
                    const float2 x0 = *(const float2*)&x[(size_t)(p0 & 0xFFFF) * DIN + 2 * lane];
                    EDGE_FMA(p0, x0);
                }
            }
        }
        *(float2*)&tmp[nl][0 * DIN + 2 * lane] = make_float2(a0x, a0y);
        *(float2*)&tmp[nl][1 * DIN + 2 * lane] = make_float2(a1x, a1y);
        *(float2*)&tmp[nl][2 * DIN + 2 * lane] = make_float2(a2x, a2y);
        *(float2*)&tmp[nl][3 * DIN + 2 * lane] = make_float2(a3x, a3y);
        *(float2*)&tmp[nl][4 * DIN + 2 * lane] = make_float2(a4x, a4y);
        *(float2*)&tmp[nl][5 * DIN + 2 * lane] = make_float2(a5x, a5y);
        *(float2*)&tmp[nl][6 * DIN + 2 * lane] = make_float2(a6x, a6y);
        *(float2*)&tmp[nl][7 * DIN + 2 * lane] = make_float2(a7x, a7y);
    }
    __syncthreads();

    // ---- Phase 2: [8 x 1152] @ [1152 x 128] ----
    const int d = tid & 127;
    const int half = tid >> 7;
    float o0 = 0.f, o1 = 0.f, o2 = 0.f, o3 = 0.f;   // nodes half, half+2, half+4, half+6

    for (int k = 0; k < KTOT; k += 4) {
        const float wv0 = weight[(k + 0) * DOUT + d];
        const float wv1 = weight[(k + 1) * DOUT + d];
        const float wv2 = weight[(k + 2) * DOUT + d];
        const float wv3 = weight[(k + 3) * DOUT + d];
        const float4 t0 = *(const float4*)&tmp[half + 0][k];
        const float4 t1 = *(const float4*)&tmp[half + 2][k];
        const float4 t2 = *(const float4*)&tmp[half + 4][k];
        const float4 t3 = *(const float4*)&tmp[half + 6][k];
        o0 += t0.x * wv0 + t0.y * wv1 + t0.z * wv2 + t0.w * wv3;
        o1 += t1.x * wv0 + t1.y * wv1 + t1.z * wv2 + t1.w * wv3;
        o2 += t2.x * wv0 + t2.y * wv1 + t2.z * wv2 + t2.w * wv3;
        o3 += t3.x * wv0 + t3.y * wv1 + t3.z * wv2 + t3.w * wv3;
    }
    for (int k = 0; k < DIN; k += 4) {
        const float wv0 = loop_w[(k + 0) * DOUT + d];
        const float wv1 = loop_w[(k + 1) * DOUT + d];
        const float wv2 = loop_w[(k + 2) * DOUT + d];
        const float wv3 = loop_w[(k + 3) * DOUT + d];
        const float4 t0 = *(const float4*)&tmp[half + 0][KTOT + k];
        const float4 t1 = *(const float4*)&tmp[half + 2][KTOT + k];
        const float4 t2 = *(const float4*)&tmp[half + 4][KTOT + k];
        const float4 t3 = *(const float4*)&tmp[half + 6][KTOT + k];
        o0 += t0.x * wv0 + t0.y * wv1 + t0.z * wv2 + t0.w * wv3;
        o1 += t1.x * wv0 + t1.y * wv1 + t1.z * wv2 + t1.w * wv3;
        o2 += t2.x * wv0 + t2.y * wv1 + t2.z * wv2 + t2.w * wv3;
        o3 += t3.x * wv0 + t3.y * wv1 + t3.z * wv2 + t3.w * wv3;
    }

    const float bias = h_bias[d];
    {
        const int n0 = nbase + half + 0;
        const int n1 = nbase + half + 2;
        const int n2 = nbase + half + 4;
        const int n3 = nbase + half + 6;
        if (n0 < N_NODES) out[(size_t)n0 * DOUT + d] = fmaxf(o0 + bias, 0.f);
        if (n1 < N_NODES) out[(size_t)n1 * DOUT + d] = fmaxf(o1 + bias, 0.f);
        if (n2 < N_NODES) out[(size_t)n2 * DOUT + d] = fmaxf(o2 + bias, 0.f);
        if (n3 < N_NODES) out[(size_t)n3 * DOUT + d] = fmaxf(o3 + bias, 0.f);
    }
}

// ---------------- launch ----------------

extern "C" void kernel_launch(void* const* d_in, const int* in_sizes, int n_in,
                              void* d_out, int out_size, void* d_ws, size_t ws_size,
                              hipStream_t stream) {
    const float* x      = (const float*)d_in[0];
    const int*   src    = (const int*)  d_in[1];
    const int*   dst    = (const int*)  d_in[2];
    const int*   ety    = (const int*)  d_in[3];
    const float* weight = (const float*)d_in[4];
    const float* w_comp = (const float*)d_in[5];
    const float* h_bias = (const float*)d_in[6];
    const float* loop_w = (const float*)d_in[7];
    float* out = (float*)d_out;

    int* deg    = (int*)d_ws;                 // N
    int* indptr = deg + N_NODES;              // N+1
    int* cursor = indptr + N_NODES + 1;       // N
    int* packed = cursor + N_NODES;           // E

    hipMemsetAsync(d_ws, 0, (size_t)(3 * N_NODES + 1) * sizeof(int), stream);

    k_hist<<<(N_EDGES + 255) / 256, 256, 0, stream>>>(dst, deg);
    k_scan<<<1, 1024, 0, stream>>>(deg, indptr);
    k_scatter<<<(N_EDGES + 255) / 256, 256, 0, stream>>>(dst, src, ety, indptr, cursor, packed);
    k_fused<<<N_NODES / NODES_PER_BLOCK, 256, 0, stream>>>(
        x, weight, w_comp, h_bias, loop_w, indptr, packed, out);
}

// Round 9
// 751.714 us; speedup vs baseline: 3.3382x; 3.3382x over previous
//
#include <hip/hip_runtime.h>

#define N_NODES 50000
#define N_EDGES 1600000
#define NREL 32
#define NBASES 8
#define DIN 128
#define DOUT 128
#define KTOT (NBASES * DIN)       // 1024
#define KSL (KTOT + DIN)          // 1152 (self-loop folded in)
#define NODES_PER_BLOCK 8

// ---------------- CSR build ----------------

__global__ void k_hist(const int* __restrict__ dst, int* __restrict__ deg) {
    int e = blockIdx.x * blockDim.x + threadIdx.x;
    if (e < N_EDGES) atomicAdd(&deg[dst[e]], 1);
}

__global__ void k_scan(const int* __restrict__ deg, int* __restrict__ indptr) {
    __shared__ int sdata[1024];
    const int T = 1024;
    int t = threadIdx.x;
    const int chunk = (N_NODES + T - 1) / T;
    int lo = t * chunk;
    int hi = lo + chunk; if (hi > N_NODES) hi = N_NODES;
    if (lo > N_NODES) lo = N_NODES;
    int s = 0;
    for (int i = lo; i < hi; ++i) s += deg[i];
    sdata[t] = s;
    __syncthreads();
    for (int off = 1; off < T; off <<= 1) {
        int v = (t >= off) ? sdata[t - off] : 0;
        __syncthreads();
        sdata[t] += v;
        __syncthreads();
    }
    int base = (t == 0) ? 0 : sdata[t - 1];
    for (int i = lo; i < hi; ++i) { indptr[i] = base; base += deg[i]; }
    if (t == T - 1) indptr[N_NODES] = sdata[T - 1];
}

// writes dst-sorted packed records: src | (etype << 16)
__global__ void k_scatter(const int* __restrict__ dst,
                          const int* __restrict__ src,
                          const int* __restrict__ ety,
                          const int* __restrict__ indptr,
                          int* __restrict__ cursor,
                          int* __restrict__ packed) {
    int e = blockIdx.x * blockDim.x + threadIdx.x;
    if (e < N_EDGES) {
        int d = dst[e];
        int pos = atomicAdd(&cursor[d], 1);
        packed[indptr[d] + pos] = src[e] | (ety[e] << 16);
    }
}

// ---------------- fused aggregate + project ----------------
// Block: 256 threads (4 waves), exactly 8 dst nodes (grid covers N exactly,
// no guards). Phase 1: wave w aggregates nodes {w, w+4}; lane covers
// d=2*lane..2*lane+1. Edge records loaded 64-wide coalesced, broadcast via
// __shfl; 4 x-row gathers in flight. Accumulators = 16 NAMED SCALARS (no
// address-taken locals -> no alloca). __launch_bounds__(256,2): the
// empirically non-spilling allocator config (cap ~128 VGPR; (256,4) capped
// at 64 and spilled 4.1 GB in round 6; by-pointer acc spilled in rounds 3/4).
// Phase 2: h = tmp[8 x 1152] @ [weight;loop_w][1152 x 128]; weight read
// straight from L2 (coalesced, same-addr LDS broadcasts for tmp).

#define EDGE_FMA(P, XV)                                                      \
    do {                                                                     \
        const float4 wA_ = *(const float4*)&wc[((P) >> 16) * NBASES];        \
        const float4 wB_ = *(const float4*)&wc[((P) >> 16) * NBASES + 4];    \
        a0x += wA_.x * (XV).x; a0y += wA_.x * (XV).y;                        \
        a1x += wA_.y * (XV).x; a1y += wA_.y * (XV).y;                        \
        a2x += wA_.z * (XV).x; a2y += wA_.z * (XV).y;                        \
        a3x += wA_.w * (XV).x; a3y += wA_.w * (XV).y;                        \
        a4x += wB_.x * (XV).x; a4y += wB_.x * (XV).y;                        \
        a5x += wB_.y * (XV).x; a5y += wB_.y * (XV).y;                        \
        a6x += wB_.z * (XV).x; a6y += wB_.z * (XV).y;                        \
        a7x += wB_.w * (XV).x; a7y += wB_.w * (XV).y;                        \
    } while (0)

__launch_bounds__(256, 2)
__global__ void k_fused(const float* __restrict__ x,
                        const float* __restrict__ weight,    // [1024][128]
                        const float* __restrict__ w_comp,    // [32][8]
                        const float* __restrict__ h_bias,    // [128]
                        const float* __restrict__ loop_w,    // [128][128]
                        const int* __restrict__ indptr,
                        const int* __restrict__ packed,
                        float* __restrict__ out) {
    __shared__ __align__(16) float wc[NREL * NBASES];            // 1 KB
    __shared__ __align__(16) float tmp[NODES_PER_BLOCK][KSL];    // 36 KB

    const int tid  = threadIdx.x;
    const int lane = tid & 63;
    const int wid  = tid >> 6;                 // 0..3
    const int nbase = blockIdx.x * NODES_PER_BLOCK;

    wc[tid & 255] = w_comp[tid & 255];         // 256 == blockDim
    __syncthreads();

    // ---- Phase 1 ----
    for (int rep = 0; rep < 2; ++rep) {
        const int nl = wid + rep * 4;
        const int node = nbase + nl;
        float a0x = 0.f, a0y = 0.f, a1x = 0.f, a1y = 0.f;
        float a2x = 0.f, a2y = 0.f, a3x = 0.f, a3y = 0.f;
        float a4x = 0.f, a4y = 0.f, a5x = 0.f, a5y = 0.f;
        float a6x = 0.f, a6y = 0.f, a7x = 0.f, a7y = 0.f;

        // self-loop row into LDS
        *(float2*)&tmp[nl][KTOT + 2 * lane] =
            *(const float2*)&x[(size_t)node * DIN + 2 * lane];

        const int beg = indptr[node], end = indptr[node + 1];
        for (int base = beg; base < end; base += 64) {
            const int cnt = min(64, end - base);
            int pk = 0;
            if (base + lane < end) pk = packed[base + lane];
            int j = 0;
            for (; j + 4 <= cnt; j += 4) {
                const int p0 = __shfl(pk, j + 0);
                const int p1 = __shfl(pk, j + 1);
                const int p2 = __shfl(pk, j + 2);
                const int p3 = __shfl(pk, j + 3);
                // 4 independent gathers in flight
                const float2 x0 = *(const float2*)&x[(size_t)(p0 & 0xFFFF) * DIN + 2 * lane];
                const float2 x1 = *(const float2*)&x[(size_t)(p1 & 0xFFFF) * DIN + 2 * lane];
                const float2 x2 = *(const float2*)&x[(size_t)(p2 & 0xFFFF) * DIN + 2 * lane];
                const float2 x3 = *(const float2*)&x[(size_t)(p3 & 0xFFFF) * DIN + 2 * lane];
                EDGE_FMA(p0, x0);
                EDGE_FMA(p1, x1);
                EDGE_FMA(p2, x2);
                EDGE_FMA(p3, x3);
            }
            for (; j < cnt; ++j) {
                const int p0 = __shfl(pk, j);
                const float2 x0 = *(const float2*)&x[(size_t)(p0 & 0xFFFF) * DIN + 2 * lane];
                EDGE_FMA(p0, x0);
            }
        }
        *(float2*)&tmp[nl][0 * DIN + 2 * lane] = make_float2(a0x, a0y);
        *(float2*)&tmp[nl][1 * DIN + 2 * lane] = make_float2(a1x, a1y);
        *(float2*)&tmp[nl][2 * DIN + 2 * lane] = make_float2(a2x, a2y);
        *(float2*)&tmp[nl][3 * DIN + 2 * lane] = make_float2(a3x, a3y);
        *(float2*)&tmp[nl][4 * DIN + 2 * lane] = make_float2(a4x, a4y);
        *(float2*)&tmp[nl][5 * DIN + 2 * lane] = make_float2(a5x, a5y);
        *(float2*)&tmp[nl][6 * DIN + 2 * lane] = make_float2(a6x, a6y);
        *(float2*)&tmp[nl][7 * DIN + 2 * lane] = make_float2(a7x, a7y);
    }
    __syncthreads();

    // ---- Phase 2: [8 x 1152] @ [1152 x 128] ----
    const int d = tid & 127;
    const int half = tid >> 7;
    float o0 = 0.f, o1 = 0.f, o2 = 0.f, o3 = 0.f;   // nodes half, half+2, half+4, half+6

    for (int k = 0; k < KTOT; k += 4) {
        const float wv0 = weight[(k + 0) * DOUT + d];
        const float wv1 = weight[(k + 1) * DOUT + d];
        const float wv2 = weight[(k + 2) * DOUT + d];
        const float wv3 = weight[(k + 3) * DOUT + d];
        const float4 t0 = *(const float4*)&tmp[half + 0][k];
        const float4 t1 = *(const float4*)&tmp[half + 2][k];
        const float4 t2 = *(const float4*)&tmp[half + 4][k];
        const float4 t3 = *(const float4*)&tmp[half + 6][k];
        o0 += t0.x * wv0 + t0.y * wv1 + t0.z * wv2 + t0.w * wv3;
        o1 += t1.x * wv0 + t1.y * wv1 + t1.z * wv2 + t1.w * wv3;
        o2 += t2.x * wv0 + t2.y * wv1 + t2.z * wv2 + t2.w * wv3;
        o3 += t3.x * wv0 + t3.y * wv1 + t3.z * wv2 + t3.w * wv3;
    }
    for (int k = 0; k < DIN; k += 4) {
        const float wv0 = loop_w[(k + 0) * DOUT + d];
        const float wv1 = loop_w[(k + 1) * DOUT + d];
        const float wv2 = loop_w[(k + 2) * DOUT + d];
        const float wv3 = loop_w[(k + 3) * DOUT + d];
        const float4 t0 = *(const float4*)&tmp[half + 0][KTOT + k];
        const float4 t1 = *(const float4*)&tmp[half + 2][KTOT + k];
        const float4 t2 = *(const float4*)&tmp[half + 4][KTOT + k];
        const float4 t3 = *(const float4*)&tmp[half + 6][KTOT + k];
        o0 += t0.x * wv0 + t0.y * wv1 + t0.z * wv2 + t0.w * wv3;
        o1 += t1.x * wv0 + t1.y * wv1 + t1.z * wv2 + t1.w * wv3;
        o2 += t2.x * wv0 + t2.y * wv1 + t2.z * wv2 + t2.w * wv3;
        o3 += t3.x * wv0 + t3.y * wv1 + t3.z * wv2 + t3.w * wv3;
    }

    const float bias = h_bias[d];
    out[(size_t)(nbase + half + 0) * DOUT + d] = fmaxf(o0 + bias, 0.f);
    out[(size_t)(nbase + half + 2) * DOUT + d] = fmaxf(o1 + bias, 0.f);
    out[(size_t)(nbase + half + 4) * DOUT + d] = fmaxf(o2 + bias, 0.f);
    out[(size_t)(nbase + half + 6) * DOUT + d] = fmaxf(o3 + bias, 0.f);
}

// ---------------- launch ----------------

extern "C" void kernel_launch(void* const* d_in, const int* in_sizes, int n_in,
                              void* d_out, int out_size, void* d_ws, size_t ws_size,
                              hipStream_t stream) {
    const float* x      = (const float*)d_in[0];
    const int*   src    = (const int*)  d_in[1];
    const int*   dst    = (const int*)  d_in[2];
    const int*   ety    = (const int*)  d_in[3];
    const float* weight = (const float*)d_in[4];
    const float* w_comp = (const float*)d_in[5];
    const float* h_bias = (const float*)d_in[6];
    const float* loop_w = (const float*)d_in[7];
    float* out = (float*)d_out;

    int* deg    = (int*)d_ws;                 // N
    int* indptr = deg + N_NODES;              // N+1
    int* cursor = indptr + N_NODES + 1;       // N
    int* packed = cursor + N_NODES;           // E

    hipMemsetAsync(d_ws, 0, (size_t)(3 * N_NODES + 1) * sizeof(int), stream);

    k_hist<<<(N_EDGES + 255) / 256, 256, 0, stream>>>(dst, deg);
    k_scan<<<1, 1024, 0, stream>>>(deg, indptr);
    k_scatter<<<(N_EDGES + 255) / 256, 256, 0, stream>>>(dst, src, ety, indptr, cursor, packed);
    k_fused<<<N_NODES / NODES_PER_BLOCK, 256, 0, stream>>>(
        x, weight, w_comp, h_bias, loop_w, indptr, packed, out);
}